// Round 3
// baseline (564.498 us; speedup 1.0000x reference)
//
#include <hip/hip_runtime.h>

#define SEQ   2048
#define BATCH 4
#define DIM   512
#define WAVE_LDS 35840
#define P_OFF    32768
#define ST_OFF   33792
#define NEG_INF  (-__builtin_inff())

typedef short short8 __attribute__((ext_vector_type(8)));
typedef float floatx4 __attribute__((ext_vector_type(4)));

__device__ __forceinline__ short to_bf16(float x){
    unsigned u = __float_as_uint(x);
    unsigned r = (u + 0x7fffu + ((u >> 16) & 1u)) >> 16;
    return (short)r;
}

__device__ __forceinline__ short8 pack8(floatx4 a, floatx4 b, float s){
    short8 r;
    r[0]=to_bf16(a[0]*s); r[1]=to_bf16(a[1]*s); r[2]=to_bf16(a[2]*s); r[3]=to_bf16(a[3]*s);
    r[4]=to_bf16(b[0]*s); r[5]=to_bf16(b[1]*s); r[6]=to_bf16(b[2]*s); r[7]=to_bf16(b[3]*s);
    return r;
}

extern "C" __global__ void __launch_bounds__(256, 1)
fa_fwd(const float* __restrict__ Qg, const float* __restrict__ Kg,
       const float* __restrict__ Vg, const unsigned char* __restrict__ Mg,
       float* __restrict__ Og)
{
    extern __shared__ __align__(16) char smem[];
    const int tid  = threadIdx.x;
    const int w    = tid >> 6;
    const int lane = tid & 63;
    const int g    = lane >> 4;
    const int c    = lane & 15;

    // XCD-affine swizzle: batch pinned to an XCD pair for KV L2 locality.
    const int x    = blockIdx.x;
    const int slot = x & 7;
    const int idx  = x >> 3;
    const int b    = slot >> 1;
    const int qt   = idx * 2 + (slot & 1);

    const int qhalf = w & 1;
    const int par   = w >> 1;
    const int q0    = qt * 32 + qhalf * 16;

    char* wbase = smem + w * WAVE_LDS;
    char* tile  = wbase;              // 32KB: K tile [32k][512d], reused as V^T [512dv][32k]
    char* Pb    = wbase + P_OFF;      // 1KB: P as [q=16][k=32] bf16 row-major

    // ---- Q -> registers (bf16, pre-scaled by 1/sqrt(D)) ----
    const float scale = 0.04419417382415922f;  // 1/sqrt(512)
    short8 qreg[16];
    {
        const float* qrow = Qg + ((size_t)(q0 + c) * BATCH + b) * DIM + g * 8;
        #pragma unroll
        for (int ks = 0; ks < 16; ++ks){
            floatx4 f0 = *(const floatx4*)(qrow + ks*32);
            floatx4 f1 = *(const floatx4*)(qrow + ks*32 + 4);
            qreg[ks] = pack8(f0, f1, scale);
        }
    }

    floatx4 oacc[32];
    #pragma unroll
    for (int i=0;i<32;++i){ floatx4 z = {0.f,0.f,0.f,0.f}; oacc[i]=z; }
    float mrow[4] = {NEG_INF, NEG_INF, NEG_INF, NEG_INF};
    float lrow[4] = {0.f,0.f,0.f,0.f};

    const int ntiles = ((q0 + 15) >> 5) + 1;   // causal: kv tiles 0..qt

    for (int t = par; t < ntiles; t += 2){
        const int kb = t * 32;

        // ---- stage K tile [32 k][512 d] bf16, XOR-swizzled 16B slots ----
        #pragma unroll 8
        for (int r = 0; r < 32; ++r){
            const float* src = Kg + ((size_t)(kb + r) * BATCH + b) * DIM + lane * 8;
            floatx4 f0 = *(const floatx4*)src;
            floatx4 f1 = *(const floatx4*)(src + 4);
            short8 v = pack8(f0, f1, 1.0f);
            *(short8*)(tile + r*1024 + ((lane*16) ^ ((r & 7) << 4))) = v;
        }

        // ---- S = Q K^T (A=Q regs, B=K from LDS) ----
        floatx4 sacc[2];
        { floatx4 z = {0.f,0.f,0.f,0.f}; sacc[0]=z; sacc[1]=z; }
        #pragma unroll
        for (int ks = 0; ks < 16; ++ks){
            #pragma unroll
            for (int nt = 0; nt < 2; ++nt){
                const int kcol = nt*16 + c;
                short8 kf = *(const short8*)(tile + kcol*1024 +
                               ((ks*64 + g*16) ^ ((kcol & 7) << 4)));
                sacc[nt] = __builtin_amdgcn_mfma_f32_16x16x32_bf16(qreg[ks], kf, sacc[nt], 0,0,0);
            }
        }

        // ---- masks + online softmax (C layout: row=g*4+jj, col=nt*16+c) ----
        float s[2][4];
        const unsigned char km0 = Mg[(kb + c) * BATCH + b];
        const unsigned char km1 = Mg[(kb + 16 + c) * BATCH + b];
        #pragma unroll
        for (int nt = 0; nt < 2; ++nt){
            const int col = kb + nt*16 + c;
            const unsigned char km = nt ? km1 : km0;
            #pragma unroll
            for (int jj = 0; jj < 4; ++jj){
                const int row = q0 + g*4 + jj;
                s[nt][jj] = (col > row || km) ? NEG_INF : sacc[nt][jj];
            }
        }
        float pmax[4];
        #pragma unroll
        for (int jj=0;jj<4;++jj) pmax[jj] = fmaxf(s[0][jj], s[1][jj]);
        #pragma unroll
        for (int msk=1; msk<16; msk<<=1){
            #pragma unroll
            for (int jj=0;jj<4;++jj)
                pmax[jj] = fmaxf(pmax[jj], __shfl_xor(pmax[jj], msk, 64));
        }
        const bool okd = (pmax[0] <= mrow[0]+8.f) && (pmax[1] <= mrow[1]+8.f)
                      && (pmax[2] <= mrow[2]+8.f) && (pmax[3] <= mrow[3]+8.f);
        if (!__all(okd)){
            float fsc[4];
            #pragma unroll
            for (int jj=0;jj<4;++jj){
                const float M = fmaxf(mrow[jj], pmax[jj]);
                const float f = (mrow[jj] == NEG_INF) ? 0.f : __expf(mrow[jj] - M);
                mrow[jj] = M; lrow[jj] *= f; fsc[jj] = f;
            }
            #pragma unroll
            for (int nt=0; nt<32; ++nt){
                #pragma unroll
                for (int jj=0; jj<4; ++jj) oacc[nt][jj] *= fsc[jj];
            }
        }
        float parr[2][4], psum[4] = {0.f,0.f,0.f,0.f};
        #pragma unroll
        for (int nt=0; nt<2; ++nt){
            #pragma unroll
            for (int jj=0; jj<4; ++jj){
                const float sv = s[nt][jj];
                const float e = (sv == NEG_INF) ? 0.f : __expf(sv - mrow[jj]);
                parr[nt][jj] = e; psum[jj] += e;
            }
        }
        #pragma unroll
        for (int msk=1; msk<16; msk<<=1){
            #pragma unroll
            for (int jj=0;jj<4;++jj) psum[jj] += __shfl_xor(psum[jj], msk, 64);
        }
        #pragma unroll
        for (int jj=0;jj<4;++jj) lrow[jj] += psum[jj];

        // ---- write P as [q=16][k=32] bf16 row-major (64B row stride) ----
        #pragma unroll
        for (int nt=0; nt<2; ++nt){
            #pragma unroll
            for (int jj=0; jj<4; ++jj){
                *(short*)(Pb + (g*4 + jj)*64 + (nt*16 + c)*2) = to_bf16(parr[nt][jj]);
            }
        }

        // ---- stage V^T tile: [dv=512][k=32] bf16, 16B-slot XOR swizzle ----
        #pragma unroll
        for (int sHalf = 0; sHalf < 2; ++sHalf){
            #pragma unroll
            for (int k0 = 0; k0 < 32; k0 += 8){
                floatx4 f[8];
                #pragma unroll
                for (int i = 0; i < 8; ++i)
                    f[i] = *(const floatx4*)(Vg + ((size_t)(kb + k0 + i) * BATCH + b) * DIM
                                             + sHalf*256 + lane*4);
                #pragma unroll
                for (int j = 0; j < 4; ++j){
                    const int dv = sHalf*256 + lane*4 + j;
                    short8 colv;
                    #pragma unroll
                    for (int i = 0; i < 8; ++i) colv[i] = to_bf16(f[i][j]);
                    *(short8*)(tile + dv*64 + ((k0*2) ^ (((dv >> 2) & 3) << 4))) = colv;
                }
            }
        }

        // ---- O += P V : A = P (plain b128), B = V^T tile (plain b128) ----
        const short8 pfrag = *(const short8*)(Pb + c*64 + g*16);
        #pragma unroll
        for (int nt = 0; nt < 32; ++nt){
            const int dv = nt*16 + c;
            short8 vf = *(const short8*)(tile + dv*64 + ((g*16) ^ (((dv >> 2) & 3) << 4)));
            oacc[nt] = __builtin_amdgcn_mfma_f32_16x16x32_bf16(pfrag, vf, oacc[nt], 0,0,0);
        }
    }

    // ---- merge kv-parity partials: waves (0,2) and (1,3) share q rows ----
    __syncthreads();
    if (par == 1){
        float* ox = (float*)tile;          // lane-linear dump, 32KB
        #pragma unroll
        for (int nt=0; nt<32; ++nt){
            #pragma unroll
            for (int jj=0; jj<4; ++jj) ox[(nt*4 + jj)*64 + lane] = oacc[nt][jj];
        }
        float* st = (float*)(wbase + ST_OFF);
        #pragma unroll
        for (int jj=0; jj<4; ++jj){ st[jj*64 + lane] = mrow[jj]; st[(4+jj)*64 + lane] = lrow[jj]; }
    }
    __syncthreads();
    if (par == 0){
        char* pbase2 = smem + (w + 2) * WAVE_LDS;
        const float* ox = (const float*)pbase2;
        const float* st = (const float*)(pbase2 + ST_OFF);
        #pragma unroll
        for (int jj=0; jj<4; ++jj){
            const float m2 = st[jj*64 + lane];
            const float l2 = st[(4+jj)*64 + lane];
            const float M  = fmaxf(mrow[jj], m2);
            const float a1 = (mrow[jj] == NEG_INF) ? 0.f : __expf(mrow[jj] - M);
            const float a2 = (m2       == NEG_INF) ? 0.f : __expf(m2 - M);
            const float L  = a1*lrow[jj] + a2*l2;
            const float inv = 1.0f / L;
            float* orow = Og + ((size_t)(q0 + g*4 + jj) * BATCH + b) * DIM + c;
            #pragma unroll
            for (int nt=0; nt<32; ++nt){
                const float o2 = ox[(nt*4 + jj)*64 + lane];
                orow[nt*16] = (a1*oacc[nt][jj] + a2*o2) * inv;
            }
        }
    }
}

extern "C" void kernel_launch(void* const* d_in, const int* in_sizes, int n_in,
                              void* d_out, int out_size, void* d_ws, size_t ws_size,
                              hipStream_t stream)
{
    const float* Q = (const float*)d_in[0];
    const float* K = (const float*)d_in[1];
    const float* V = (const float*)d_in[2];
    const unsigned char* M = (const unsigned char*)d_in[3];
    float* O = (float*)d_out;
    (void)in_sizes; (void)n_in; (void)out_size; (void)d_ws; (void)ws_size;

    hipFuncSetAttribute(reinterpret_cast<const void*>(fa_fwd),
                        hipFuncAttributeMaxDynamicSharedMemorySize, 4*WAVE_LDS);
    fa_fwd<<<256, 256, 4*WAVE_LDS, stream>>>(Q, K, V, M, O);
}

// Round 4
// 277.009 us; speedup vs baseline: 2.0378x; 2.0378x over previous
//
#include <hip/hip_runtime.h>

#define SEQ   2048
#define BATCH 4
#define DIM   512
#define WAVE_LDS 35840
#define P_OFF    32768
#define ST_OFF   33792
#define NEG_INF  (-__builtin_inff())

typedef short short8 __attribute__((ext_vector_type(8)));
typedef float floatx4 __attribute__((ext_vector_type(4)));

__device__ __forceinline__ short to_bf16(float x){
    unsigned u = __float_as_uint(x);
    unsigned r = (u + 0x7fffu + ((u >> 16) & 1u)) >> 16;
    return (short)r;
}

__device__ __forceinline__ short8 pack8(floatx4 a, floatx4 b, float s){
    short8 r;
    r[0]=to_bf16(a[0]*s); r[1]=to_bf16(a[1]*s); r[2]=to_bf16(a[2]*s); r[3]=to_bf16(a[3]*s);
    r[4]=to_bf16(b[0]*s); r[5]=to_bf16(b[1]*s); r[6]=to_bf16(b[2]*s); r[7]=to_bf16(b[3]*s);
    return r;
}

// K [k][b][d] fp32  ->  Kb [b][k][d] bf16.  Coalesced reads (lane ~ d).
extern "C" __global__ void __launch_bounds__(256)
conv_k(const float* __restrict__ K, short* __restrict__ Kb)
{
    const int t    = blockIdx.x * 256 + threadIdx.x;   // 524288 threads
    const int d8   = t & 63;                           // 8-elem d chunk
    const int row  = t >> 6;                           // k*BATCH + b
    const int k    = row >> 2;
    const int b    = row & 3;
    const float* src = K + (size_t)row * DIM + d8 * 8;
    floatx4 f0 = *(const floatx4*)src;
    floatx4 f1 = *(const floatx4*)(src + 4);
    *(short8*)(Kb + ((size_t)b * SEQ + k) * DIM + d8 * 8) = pack8(f0, f1, 1.0f);
}

// V [k][b][dv] fp32 -> Vt [b][dv][k] bf16 (transposed). Reads coalesced (lane ~ dv).
extern "C" __global__ void __launch_bounds__(256)
conv_v(const float* __restrict__ V, short* __restrict__ Vt)
{
    const int t    = blockIdx.x * 256 + threadIdx.x;   // 524288 threads
    const int dv   = t & 511;
    const int rest = t >> 9;
    const int kc   = rest & 255;                       // 8-k chunk
    const int b    = rest >> 8;
    short8 colv;
    #pragma unroll
    for (int i = 0; i < 8; ++i){
        const float f = V[((size_t)(kc*8 + i) * BATCH + b) * DIM + dv];
        colv[i] = to_bf16(f);
    }
    *(short8*)(Vt + ((size_t)b * DIM + dv) * SEQ + kc * 8) = colv;
}

extern "C" __global__ void __launch_bounds__(256, 1)
fa_fwd(const float* __restrict__ Qg, const short* __restrict__ Kb,
       const short* __restrict__ Vt, const unsigned char* __restrict__ Mg,
       float* __restrict__ Og)
{
    extern __shared__ __align__(16) char smem[];
    const int tid  = threadIdx.x;
    const int w    = tid >> 6;
    const int lane = tid & 63;
    const int g    = lane >> 4;
    const int c    = lane & 15;

    // XCD-affine swizzle: batch pinned to an XCD pair for KV L2 locality.
    const int x    = blockIdx.x;
    const int slot = x & 7;
    const int idx  = x >> 3;
    const int b    = slot >> 1;
    const int qt   = idx * 2 + (slot & 1);

    const int qhalf = w & 1;
    const int par   = w >> 1;
    const int q0    = qt * 32 + qhalf * 16;

    char* wbase = smem + w * WAVE_LDS;
    char* tile  = wbase;              // used only for the merge dump now
    char* Pb    = wbase + P_OFF;      // 1KB: P as [q=16][k=32] bf16 row-major

    const short* Kbb = Kb + (size_t)b * SEQ * DIM;
    const short* Vtb = Vt + (size_t)b * DIM * SEQ;

    // ---- Q -> registers (bf16, pre-scaled by 1/sqrt(D)) ----
    const float scale = 0.04419417382415922f;  // 1/sqrt(512)
    short8 qreg[16];
    {
        const float* qrow = Qg + ((size_t)(q0 + c) * BATCH + b) * DIM + g * 8;
        #pragma unroll
        for (int ks = 0; ks < 16; ++ks){
            floatx4 f0 = *(const floatx4*)(qrow + ks*32);
            floatx4 f1 = *(const floatx4*)(qrow + ks*32 + 4);
            qreg[ks] = pack8(f0, f1, scale);
        }
    }

    floatx4 oacc[32];
    #pragma unroll
    for (int i=0;i<32;++i){ floatx4 z = {0.f,0.f,0.f,0.f}; oacc[i]=z; }
    float mrow[4] = {NEG_INF, NEG_INF, NEG_INF, NEG_INF};
    float lrow[4] = {0.f,0.f,0.f,0.f};

    const int ntiles = ((q0 + 15) >> 5) + 1;   // causal: kv tiles 0..qt

    for (int t = par; t < ntiles; t += 2){
        const int kb = t * 32;

        // ---- S = Q K^T : B-frags loaded straight from bf16 K rows (L2) ----
        floatx4 sacc[2];
        { floatx4 z = {0.f,0.f,0.f,0.f}; sacc[0]=z; sacc[1]=z; }
        #pragma unroll
        for (int ks = 0; ks < 16; ++ks){
            #pragma unroll
            for (int nt = 0; nt < 2; ++nt){
                const int kcol = kb + nt*16 + c;
                const short8 kf = *(const short8*)(Kbb + (size_t)kcol * DIM + ks*32 + g*8);
                sacc[nt] = __builtin_amdgcn_mfma_f32_16x16x32_bf16(qreg[ks], kf, sacc[nt], 0,0,0);
            }
        }

        // ---- masks + online softmax (C layout: row=g*4+jj, col=nt*16+c) ----
        float s[2][4];
        const unsigned char km0 = Mg[(kb + c) * BATCH + b];
        const unsigned char km1 = Mg[(kb + 16 + c) * BATCH + b];
        #pragma unroll
        for (int nt = 0; nt < 2; ++nt){
            const int col = kb + nt*16 + c;
            const unsigned char km = nt ? km1 : km0;
            #pragma unroll
            for (int jj = 0; jj < 4; ++jj){
                const int row = q0 + g*4 + jj;
                s[nt][jj] = (col > row || km) ? NEG_INF : sacc[nt][jj];
            }
        }
        float pmax[4];
        #pragma unroll
        for (int jj=0;jj<4;++jj) pmax[jj] = fmaxf(s[0][jj], s[1][jj]);
        #pragma unroll
        for (int msk=1; msk<16; msk<<=1){
            #pragma unroll
            for (int jj=0;jj<4;++jj)
                pmax[jj] = fmaxf(pmax[jj], __shfl_xor(pmax[jj], msk, 64));
        }
        const bool okd = (pmax[0] <= mrow[0]+8.f) && (pmax[1] <= mrow[1]+8.f)
                      && (pmax[2] <= mrow[2]+8.f) && (pmax[3] <= mrow[3]+8.f);
        if (!__all(okd)){
            float fsc[4];
            #pragma unroll
            for (int jj=0;jj<4;++jj){
                const float M = fmaxf(mrow[jj], pmax[jj]);
                const float f = (mrow[jj] == NEG_INF) ? 0.f : __expf(mrow[jj] - M);
                mrow[jj] = M; lrow[jj] *= f; fsc[jj] = f;
            }
            #pragma unroll
            for (int nt=0; nt<32; ++nt){
                #pragma unroll
                for (int jj=0; jj<4; ++jj) oacc[nt][jj] *= fsc[jj];
            }
        }
        float parr[2][4], psum[4] = {0.f,0.f,0.f,0.f};
        #pragma unroll
        for (int nt=0; nt<2; ++nt){
            #pragma unroll
            for (int jj=0; jj<4; ++jj){
                const float sv = s[nt][jj];
                const float e = (sv == NEG_INF) ? 0.f : __expf(sv - mrow[jj]);
                parr[nt][jj] = e; psum[jj] += e;
            }
        }
        #pragma unroll
        for (int msk=1; msk<16; msk<<=1){
            #pragma unroll
            for (int jj=0;jj<4;++jj) psum[jj] += __shfl_xor(psum[jj], msk, 64);
        }
        #pragma unroll
        for (int jj=0;jj<4;++jj) lrow[jj] += psum[jj];

        // ---- write P as [q=16][k=32] bf16 row-major (64B row stride) ----
        #pragma unroll
        for (int nt=0; nt<2; ++nt){
            #pragma unroll
            for (int jj=0; jj<4; ++jj){
                *(short*)(Pb + (g*4 + jj)*64 + (nt*16 + c)*2) = to_bf16(parr[nt][jj]);
            }
        }

        // ---- O += P V : A = P (LDS b128), B = V^T rows straight from L2 ----
        const short8 pfrag = *(const short8*)(Pb + c*64 + g*16);
        #pragma unroll
        for (int nt = 0; nt < 32; ++nt){
            const int dv = nt*16 + c;
            const short8 vf = *(const short8*)(Vtb + (size_t)dv * SEQ + kb + g*8);
            oacc[nt] = __builtin_amdgcn_mfma_f32_16x16x32_bf16(pfrag, vf, oacc[nt], 0,0,0);
        }
    }

    // ---- merge kv-parity partials: waves (0,2) and (1,3) share q rows ----
    __syncthreads();
    if (par == 1){
        float* ox = (float*)tile;          // lane-linear dump, 32KB
        #pragma unroll
        for (int nt=0; nt<32; ++nt){
            #pragma unroll
            for (int jj=0; jj<4; ++jj) ox[(nt*4 + jj)*64 + lane] = oacc[nt][jj];
        }
        float* st = (float*)(wbase + ST_OFF);
        #pragma unroll
        for (int jj=0; jj<4; ++jj){ st[jj*64 + lane] = mrow[jj]; st[(4+jj)*64 + lane] = lrow[jj]; }
    }
    __syncthreads();
    if (par == 0){
        char* pbase2 = smem + (w + 2) * WAVE_LDS;
        const float* ox = (const float*)pbase2;
        const float* st = (const float*)(pbase2 + ST_OFF);
        #pragma unroll
        for (int jj=0; jj<4; ++jj){
            const float m2 = st[jj*64 + lane];
            const float l2 = st[(4+jj)*64 + lane];
            const float M  = fmaxf(mrow[jj], m2);
            const float a1 = (mrow[jj] == NEG_INF) ? 0.f : __expf(mrow[jj] - M);
            const float a2 = (m2       == NEG_INF) ? 0.f : __expf(m2 - M);
            const float L  = a1*lrow[jj] + a2*l2;
            const float inv = 1.0f / L;
            float* orow = Og + ((size_t)(q0 + g*4 + jj) * BATCH + b) * DIM + c;
            #pragma unroll
            for (int nt=0; nt<32; ++nt){
                const float o2 = ox[(nt*4 + jj)*64 + lane];
                orow[nt*16] = (a1*oacc[nt][jj] + a2*o2) * inv;
            }
        }
    }
}

extern "C" void kernel_launch(void* const* d_in, const int* in_sizes, int n_in,
                              void* d_out, int out_size, void* d_ws, size_t ws_size,
                              hipStream_t stream)
{
    const float* Q = (const float*)d_in[0];
    const float* K = (const float*)d_in[1];
    const float* V = (const float*)d_in[2];
    const unsigned char* M = (const unsigned char*)d_in[3];
    float* O = (float*)d_out;
    (void)in_sizes; (void)n_in; (void)out_size; (void)ws_size;

    short* Kb = (short*)d_ws;                               // 8.4 MB
    short* Vt = Kb + (size_t)BATCH * SEQ * DIM;             // 8.4 MB

    conv_k<<<2048, 256, 0, stream>>>(K, Kb);
    conv_v<<<2048, 256, 0, stream>>>(V, Vt);

    hipFuncSetAttribute(reinterpret_cast<const void*>(fa_fwd),
                        hipFuncAttributeMaxDynamicSharedMemorySize, 4*WAVE_LDS);
    fa_fwd<<<256, 256, 4*WAVE_LDS, stream>>>(Q, Kb, Vt, M, O);
}